// Round 10
// baseline (866.227 us; speedup 1.0000x reference)
//
#include <hip/hip_runtime.h>

// RFNetwork recurrence (in_in_p dead; P = out_in_p):
//   out_t = (W+P) @ x_t ; P = colrenorm(rowrenorm(P + l*outer(out,x)))
// 1D row decomposition, P IN REGISTERS:
//   64 blocks x 1024 threads; wave w = row (16 rows/block); lane l holds the
//   row's cols {4l..4l+3} + 256k (4 f32x4) in REGISTERS p[4]. One-step-lazy
//   column factor f[4] also in registers (P_true = Pt * f).
//   pass1: pf=p*f; out_i = sum (pf+W)x (wave shuffle-reduce); R_i = sum pf
//          rf from R1 = R + l*out*sx[t]  (all lanes redundantly; no LDS bcast)
//   pass2: p <- rf*(pf + l*out*x)   (pure register FMAs; P never moves!)
//   colsum: LDS tree 16->4->1 waves -> publish 4KB partial -> flagP
//   reducers (blocks 0..15, col-slice 64 each): poll 64 flagP, read 64x256B,
//   LDS tree, compute f = s>1?1/s:1, publish 256B + flagF (in-wave vmcnt).
//   consumers: poll 16-flag line (1 line), read 4KB f into registers.
// Single exchange per step (2 small hops, ~0.5MB/step device-wide).
// Overwrite safety WITHOUT parity dbuf: block b's publish(t+1) happens after
// its flagF>=t poll; flagF[g]=t implies reducer g finished ALL Spart(t) reads
// -> no read/write race. Reducer writes F(t+1) after seeing all flagP>=t+2,
// which consumers set only after their F(t) reads completed -> F single-buf.
// All reduction trees fixed -> bit-deterministic. No data atomics.

typedef float f32x4 __attribute__((ext_vector_type(4)));

#define T_STEPS 128
#define N 1024
#define N4 256
#define NB 64
#define RPB 16
#define NT 1024
#define NW 16
#define NRED 16
#define LMBDA 0.01f

__global__ __launch_bounds__(NT) void rf1d_kernel(
    const float* __restrict__ X,      // [T][N]
    const float* __restrict__ W,      // [N][N]
    float* __restrict__ OUT,          // [T][N]
    f32x4* __restrict__ Spart,        // [NB][N4] colsum partials
    f32x4* __restrict__ F,            // [N4] column factors
    unsigned* __restrict__ flagP,     // [NB]
    unsigned* __restrict__ flagF) {   // [NRED]
  __shared__ f32x4 SLw[NW][N4];   // 64 KB: pass2 values / reducer slab buf
  __shared__ f32x4 SL2[4][N4];    // 16 KB: tree stage / reducer stage
  __shared__ float sxAll[T_STEPS];

  const int tid = threadIdx.x;
  const int b = blockIdx.x;
  const int w = tid >> 6, l = tid & 63;
  const int row = b * RPB + w;

  const f32x4* X4 = (const f32x4*)X;
  const f32x4* W4 = (const f32x4*)W;

  // ---- init: state in registers ----
  f32x4 p[4], f[4], wr[4], xv[4];
#pragma unroll
  for (int k = 0; k < 4; ++k) {
    p[k] = f32x4{0.f, 0.f, 0.f, 0.f};
    f[k] = f32x4{1.f, 1.f, 1.f, 1.f};
    wr[k] = W4[(size_t)row * N4 + l + 64 * k];
    xv[k] = X4[l + 64 * k];  // x[0]
  }
  // sx[t] for all steps (X fixed input): wave w handles t = w, w+16, ...
  for (int tt = w; tt < T_STEPS; tt += NW) {
    float a = 0.f;
#pragma unroll
    for (int k = 0; k < 4; ++k) {
      f32x4 x = X4[tt * N4 + l + 64 * k];
      a += x.x + x.y + x.z + x.w;
    }
#pragma unroll
    for (int off = 1; off < 64; off <<= 1) a += __shfl_xor(a, off, 64);
    if (l == 0) sxAll[tt] = a;
  }
  __syncthreads();

  for (int t = 0; t < T_STEPS; ++t) {
    const unsigned tg = t + 1u;

    // ---- pass1: out_i, R_i (registers + wave reduce) ----
    float a_out = 0.f, a_R = 0.f;
#pragma unroll
    for (int k = 0; k < 4; ++k) {
      f32x4 pf = p[k] * f[k];
      a_R += pf.x + pf.y + pf.z + pf.w;
      f32x4 s = (pf + wr[k]) * xv[k];
      a_out += s.x + s.y + s.z + s.w;
    }
#pragma unroll
    for (int off = 1; off < 64; off <<= 1) a_out += __shfl_xor(a_out, off, 64);
#pragma unroll
    for (int off = 1; off < 64; off <<= 1) a_R += __shfl_xor(a_R, off, 64);
    const float ol = LMBDA * a_out;
    const float R1 = a_R + ol * sxAll[t];
    const float rf = (R1 > 1.f) ? 1.f / R1 : 1.f;  // MAX_POST = 1
    if (l == 0) OUT[(size_t)t * N + row] = a_out;
    if (t == T_STEPS - 1) break;  // state past last output is dead work

    // ---- pass2 in registers + LDS stage0 ----
#pragma unroll
    for (int k = 0; k < 4; ++k) {
      f32x4 v = rf * (p[k] * f[k] + ol * xv[k]);  // round-6 association
      p[k] = v;
      SLw[w][l + 64 * k] = v;
    }
    __syncthreads();
    // ---- stage1: 16 -> 4 ----
    {
      const int qr = tid >> 8, c4 = tid & 255;
      SL2[qr][c4] = (SLw[4 * qr][c4] + SLw[4 * qr + 1][c4]) +
                    (SLw[4 * qr + 2][c4] + SLw[4 * qr + 3][c4]);
    }
    __syncthreads();
    // ---- stage2: 4 -> 1, publish partial colsum (4 KB) ----
    if (tid < N4) {
      f32x4 s = (SL2[0][tid] + SL2[1][tid]) + (SL2[2][tid] + SL2[3][tid]);
      f32x4* dst = Spart + (size_t)b * N4 + tid;
      asm volatile("global_store_dwordx4 %0, %1, off sc0 sc1"
                   :: "v"(dst), "v"(s) : "memory");
    }
    // prefetch x(t+1) while stores drain (xv of t already consumed by pass2)
#pragma unroll
    for (int k = 0; k < 4; ++k) xv[k] = X4[(t + 1) * N4 + l + 64 * k];
    __syncthreads();  // drain: publishing waves' vmcnt at barrier arrival
    if (tid == 0)
      __hip_atomic_store(&flagP[b], tg, __ATOMIC_RELAXED, __HIP_MEMORY_SCOPE_AGENT);

    // ---- reducer role: blocks 0..15, column slice [64b, 64b+64) ----
    if (b < NRED) {
      if (w == 0) {  // poll all 64 producer flags (64 lanes x 1 dword)
        for (;;) {
          unsigned v = __hip_atomic_load(&flagP[l], __ATOMIC_RELAXED,
                                         __HIP_MEMORY_SCOPE_AGENT);
          if (__all(v >= tg)) break;
          __builtin_amdgcn_s_sleep(1);
        }
      }
      __syncthreads();
      {  // read all 64 slabs' 16-chunk slice: 1 dwordx4/thread
        const int s = tid >> 4, cc = tid & 15;
        f32x4 vv;
        const f32x4* ap = Spart + (size_t)s * N4 + b * 16 + cc;
        asm volatile("global_load_dwordx4 %0, %1, off sc0 sc1\n\ts_waitcnt vmcnt(0)"
                     : "=v"(vv) : "v"(ap) : "memory");
        __builtin_amdgcn_sched_barrier(0);
        ((f32x4*)SLw)[s * 16 + cc] = vv;  // RSL[64][16] aliases SLw (dead)
      }
      __syncthreads();
      if (tid < 256) {  // 64 -> 16
        const int g4 = tid >> 4, cc = tid & 15;
        const f32x4* RSL = (const f32x4*)SLw;
        ((f32x4*)SL2)[g4 * 16 + cc] =
            (RSL[(4 * g4 + 0) * 16 + cc] + RSL[(4 * g4 + 1) * 16 + cc]) +
            (RSL[(4 * g4 + 2) * 16 + cc] + RSL[(4 * g4 + 3) * 16 + cc]);
      }
      __syncthreads();
      if (tid < 16) {  // 16 -> 1, compute f, publish (wave0 only)
        const f32x4* RSL2 = (const f32x4*)SL2;
        f32x4 s = f32x4{0.f, 0.f, 0.f, 0.f};
#pragma unroll
        for (int g4 = 0; g4 < 16; ++g4) s += RSL2[g4 * 16 + tid];
        f32x4 fc;
        fc.x = (s.x > 1.f) ? 1.f / s.x : 1.f;  // MAX_PRE = 1
        fc.y = (s.y > 1.f) ? 1.f / s.y : 1.f;
        fc.z = (s.z > 1.f) ? 1.f / s.z : 1.f;
        fc.w = (s.w > 1.f) ? 1.f / s.w : 1.f;
        f32x4* dst = F + b * 16 + tid;
        asm volatile("global_store_dwordx4 %0, %1, off sc0 sc1"
                     :: "v"(dst), "v"(fc) : "memory");
      }
      if (w == 0) {  // vmcnt is per-WAVE: one wait covers all 16 lanes' stores
        asm volatile("s_waitcnt vmcnt(0)" ::: "memory");
        __builtin_amdgcn_sched_barrier(0);
        if (l == 0)
          __hip_atomic_store(&flagF[b], tg, __ATOMIC_RELAXED, __HIP_MEMORY_SCOPE_AGENT);
      }
    }

    // ---- consumer: poll the single 16-flag line, read f (4 KB) ----
    if (w == 0) {
      for (;;) {
        unsigned v = tg;
        if (l < NRED)
          v = __hip_atomic_load(&flagF[l], __ATOMIC_RELAXED, __HIP_MEMORY_SCOPE_AGENT);
        if (__all(v >= tg)) break;
        __builtin_amdgcn_s_sleep(1);
      }
    }
    __syncthreads();
    {
      f32x4 f0, f1, f2, f3;
      asm volatile("global_load_dwordx4 %0, %4, off sc0 sc1\n\t"
                   "global_load_dwordx4 %1, %5, off sc0 sc1\n\t"
                   "global_load_dwordx4 %2, %6, off sc0 sc1\n\t"
                   "global_load_dwordx4 %3, %7, off sc0 sc1\n\t"
                   "s_waitcnt vmcnt(0)"
                   : "=v"(f0), "=v"(f1), "=v"(f2), "=v"(f3)
                   : "v"(F + l), "v"(F + l + 64), "v"(F + l + 128), "v"(F + l + 192)
                   : "memory");
      __builtin_amdgcn_sched_barrier(0);
      f[0] = f0; f[1] = f1; f[2] = f2; f[3] = f3;
    }
  }
}

extern "C" void kernel_launch(void* const* d_in, const int* in_sizes, int n_in,
                              void* d_out, int out_size, void* d_ws, size_t ws_size,
                              hipStream_t stream) {
  const float* X = (const float*)d_in[0];   // inputs [128][1024]
  const float* W = (const float*)d_in[2];   // out_in_fixed [1024][1024]
  float* OUT = (float*)d_out;               // [128][1024] f32

  char* ws = (char*)d_ws;
  // layout: flagP (256B) | flagF (64B) | pad to 1KB | Spart 256KB | F 4KB
  unsigned* flagP = (unsigned*)ws;
  unsigned* flagF = (unsigned*)(ws + 256);
  f32x4* Spart = (f32x4*)(ws + 1024);
  f32x4* F = (f32x4*)(ws + 1024 + (size_t)NB * N4 * sizeof(f32x4));

  // flags zero each (graph-replayed) launch; monotone within a launch.
  // Data buffers need no clear: every read is flag-gated.
  hipMemsetAsync(ws, 0, 1024, stream);

  hipLaunchKernelGGL(rf1d_kernel, dim3(NB), dim3(NT), 0, stream,
                     X, W, OUT, Spart, F, flagP, flagF);
}

// Round 13
// 639.881 us; speedup vs baseline: 1.3537x; 1.3537x over previous
//
#include <hip/hip_runtime.h>

// RFNetwork recurrence (in_in_p dead; P = out_in_p):
//   out_t = (W+P) @ x_t ; P = colrenorm(rowrenorm(P + l*outer(out,x)))
// 16x16 grid, block (r,c) owns 64x64 tile of P_tilde in LDS (one-step-lazy
// column factor f: P_true = Pt * diag(f)).
// Sync skeleton = round 9 VERBATIM (passed, 632us):
//   publish A (single-writer 512B span) -> drain sync -> fAr/fAc flag store
//   -> per-thread poll of own 4 flags (one dwordx4, 1 line) -> strided data
//   read; pass2; safety pollA-col; publish B (single-writer 256B span) ->
//   drain sync -> fBc/fBr -> per-thread poll -> data read -> f update;
//   safety pollB-row. Parity double-buffered data slots.
// RULE (from rounds 11/12 failures): cross-block DATA lines are strictly
// single-writer; only 4B flag words are multi-writer (atomic stores only).
// Compute fixes vs round 9 (intra-block only):
//  - pass1 is PURE-READ (no Pt*f writeback): kills the 4.2M LDS bank
//    conflicts (b128 writes to XOR-swizzled slots conflict; reads don't).
//  - pass2 uses round-6 association rf*(Pt*f + ol*x): absmax back to ~0.5.
// All reduction trees fixed -> bit-deterministic. No data atomics.

typedef float f32x4 __attribute__((ext_vector_type(4)));
typedef float f32x2 __attribute__((ext_vector_type(2)));
typedef unsigned u32x4 __attribute__((ext_vector_type(4)));

#define T_STEPS 128
#define N 1024
#define GR 16
#define GC 16
#define TB 64
#define NT 256
#define LMBDA 0.01f

__global__ __launch_bounds__(NT) void rf2d_kernel(
    const float* __restrict__ X,    // [T][N]
    const float* __restrict__ W,    // [N][N]
    float* __restrict__ OUT,        // [T][N]
    f32x2* __restrict__ OutP,       // [2][GC][N] (out,R) partials
    float* __restrict__ Scol,       // [2][GR][N] colsum partials
    unsigned* __restrict__ fAr,     // [GR][GC] A-publish flags, row-major
    unsigned* __restrict__ fAc,     // [GC][GR] A-publish flags, col-major
    unsigned* __restrict__ fBc,     // [GC][GR] B-publish flags, col-major
    unsigned* __restrict__ fBr) {   // [GR][GC] B-publish flags, row-major
  __shared__ float Pl[TB * TB];     // 16 KB tile, f32x4-chunk XOR swizzle
  __shared__ float f_loc[TB];
  __shared__ float rfl[TB], oll[TB];
  __shared__ float SLc[4][TB];
  __shared__ float SLd[4][TB];
  __shared__ float sxAll[T_STEPS];

  const int tid = threadIdx.x;
  const int b = blockIdx.x;
  const int r = b >> 4, c = b & 15;
  const int grow = r * TB, gcol = c * TB;
  const int r_loc = tid >> 2, q = tid & 3;   // pass1: 4 lanes per row
  const int c_loc = tid & 63, rg = tid >> 6; // pass2: column slice

  // ---- init ----
  for (int i = tid; i < TB * TB; i += NT) Pl[i] = 0.f;
  if (tid < TB) f_loc[tid] = 1.f;
  {  // sx[t] for all steps (X fixed): 2 threads per row, fixed combine order
    const int rowi = tid >> 1, half = tid & 1;
    const f32x4* Xr = (const f32x4*)(X + (size_t)rowi * N) + half * 128;
    f32x4 acc = {0.f, 0.f, 0.f, 0.f};
    for (int j = 0; j < 128; ++j) acc += Xr[j];
    ((float*)SLc)[tid] = (acc.x + acc.y) + (acc.z + acc.w);
  }
  __syncthreads();
  if (tid < T_STEPS)
    sxAll[tid] = ((float*)SLc)[2 * tid] + ((float*)SLc)[2 * tid + 1];

  f32x4 wr[4];
#pragma unroll
  for (int k = 0; k < 4; ++k)
    wr[k] = *(const f32x4*)(W + (size_t)(grow + r_loc) * N + gcol + 16 * q + 4 * k);

  // W.x partial for t=0
  float wrx = 0.f;
  {
    const f32x4* Xn = (const f32x4*)(X + gcol);
#pragma unroll
    for (int k = 0; k < 4; ++k) {
      f32x4 xv = Xn[4 * q + k];
      wrx += (wr[k].x * xv.x + wr[k].y * xv.y) + (wr[k].z * xv.z + wr[k].w * xv.w);
    }
  }
  __syncthreads();

  for (int t = 0; t < T_STEPS; ++t) {
    const int p = t & 1;
    const unsigned tg = t + 1u;

    // ---- pass1: tile partials (PURE LDS reads; no writeback) ----
    float a_out = wrx, a_R = 0.f;
    {
      const f32x4* PlV = (const f32x4*)Pl;
      const f32x4* FV = (const f32x4*)f_loc;
      const f32x4* XV = (const f32x4*)(X + (size_t)t * N + gcol);
#pragma unroll
      for (int k = 0; k < 4; ++k) {
        const int lc = 4 * q + k;
        f32x4 pv = PlV[r_loc * 16 + (lc ^ (r_loc & 15))];
        f32x4 fv = FV[lc];
        f32x4 xv = XV[lc];
        f32x4 pf = pv * fv;
        a_R += (pf.x + pf.y) + (pf.z + pf.w);
        a_out += (pf.x * xv.x + pf.y * xv.y) + (pf.z * xv.z + pf.w * xv.w);
      }
    }
    a_out += __shfl_xor(a_out, 1, 64); a_out += __shfl_xor(a_out, 2, 64);
    a_R   += __shfl_xor(a_R, 1, 64);   a_R   += __shfl_xor(a_R, 2, 64);

    // ---- publish A: (out,R) f32x2 per row (single-writer 512B span) ----
    if (q == 0) {
      f32x2 v; v.x = a_out; v.y = a_R;
      f32x2* dst = OutP + (size_t)p * GC * N + (size_t)c * N + grow + r_loc;
      asm volatile("global_store_dwordx2 %0, %1, off sc0 sc1"
                   :: "v"(dst), "v"(v) : "memory");
    }
    __syncthreads();  // drain-A: all waves' stores at LLC (vmcnt(0) pre-barrier)
    if (tid == 0) {
      __hip_atomic_store(&fAr[r * GC + c], tg, __ATOMIC_RELAXED, __HIP_MEMORY_SCOPE_AGENT);
      __hip_atomic_store(&fAc[c * GR + r], tg, __ATOMIC_RELAXED, __HIP_MEMORY_SCOPE_AGENT);
    }

    // ---- per-thread poll of own 4 producer flags (one dwordx4, 1 line) ----
    {
      const unsigned* fp = fAr + r * GC + 4 * q;
      u32x4 fv;
      for (;;) {
        asm volatile("global_load_dwordx4 %0, %1, off sc0 sc1\n\ts_waitcnt vmcnt(0)"
                     : "=v"(fv) : "v"(fp) : "memory");
        __builtin_amdgcn_sched_barrier(0);
        if (fv.x >= tg && fv.y >= tg && fv.z >= tg && fv.w >= tg) break;
        __builtin_amdgcn_s_sleep(1);
      }
    }
    // ---- read own 4 chunks, reduce ----
    {
      f32x2 v0, v1, v2, v3;
      const f32x2* baseA = OutP + (size_t)p * GC * N + grow + r_loc;
      asm volatile("global_load_dwordx2 %0, %4, off sc0 sc1\n\t"
                   "global_load_dwordx2 %1, %5, off sc0 sc1\n\t"
                   "global_load_dwordx2 %2, %6, off sc0 sc1\n\t"
                   "global_load_dwordx2 %3, %7, off sc0 sc1\n\t"
                   "s_waitcnt vmcnt(0)"
                   : "=v"(v0), "=v"(v1), "=v"(v2), "=v"(v3)
                   : "v"(baseA + (size_t)(4 * q + 0) * N),
                     "v"(baseA + (size_t)(4 * q + 1) * N),
                     "v"(baseA + (size_t)(4 * q + 2) * N),
                     "v"(baseA + (size_t)(4 * q + 3) * N)
                   : "memory");
      __builtin_amdgcn_sched_barrier(0);
      float po = (v0.x + v1.x) + (v2.x + v3.x);
      float pR = (v0.y + v1.y) + (v2.y + v3.y);
      po += __shfl_xor(po, 1, 64); po += __shfl_xor(po, 2, 64);
      pR += __shfl_xor(pR, 1, 64); pR += __shfl_xor(pR, 2, 64);
      float ol = LMBDA * po;
      float R1 = pR + ol * sxAll[t];
      float rf = (R1 > 1.f) ? 1.f / R1 : 1.f;  // MAX_POST = 1
      if (q == 0) { rfl[r_loc] = rf; oll[r_loc] = ol; }
      if (c == 0 && q == 0) OUT[(size_t)t * N + grow + r_loc] = po;
    }
    if (t == T_STEPS - 1) break;  // state past last output is dead work
    __syncthreads();  // (b) rfl/oll visible

    // ---- pass2 (round-6 association): v = rf*(Pt*f + ol*x) ----
    {
      const float xc = X[(size_t)t * N + gcol + c_loc];
      const float fc = f_loc[c_loc];
      float cacc = 0.f;
#pragma unroll
      for (int rr = 0; rr < 16; ++rr) {
        const int row = rg * 16 + rr;
        const int idx = row * 64 + ((((c_loc >> 2) ^ (row & 15))) << 2) + (c_loc & 3);
        float v = rfl[row] * (Pl[idx] * fc + oll[row] * xc);
        Pl[idx] = v;
        cacc += v;
      }
      SLc[rg][c_loc] = cacc;
    }
    // safety pollA-col (gates publish B(t)): transitive overwrite proof
    if (tid < 16) {
      while (__hip_atomic_load(&fAc[c * GR + tid], __ATOMIC_RELAXED,
                               __HIP_MEMORY_SCOPE_AGENT) < tg)
        __builtin_amdgcn_s_sleep(1);
    }
    __syncthreads();  // (c) SLc visible; safety poll done

    // ---- publish B: colsum float per column (single-writer 256B span) ----
    if (tid < TB) {
      float scol = (SLc[0][tid] + SLc[1][tid]) + (SLc[2][tid] + SLc[3][tid]);
      float* dst = Scol + (size_t)p * GR * N + (size_t)r * N + gcol + tid;
      asm volatile("global_store_dword %0, %1, off sc0 sc1"
                   :: "v"(dst), "v"(scol) : "memory");
    }
    __syncthreads();  // drain-B
    if (tid == 0) {
      __hip_atomic_store(&fBc[c * GR + r], tg, __ATOMIC_RELAXED, __HIP_MEMORY_SCOPE_AGENT);
      __hip_atomic_store(&fBr[r * GC + c], tg, __ATOMIC_RELAXED, __HIP_MEMORY_SCOPE_AGENT);
    }

    // ---- hidden under B-wait: W.x partial for step t+1 ----
    wrx = 0.f;
    {
      const f32x4* Xn = (const f32x4*)(X + (size_t)(t + 1) * N + gcol);
#pragma unroll
      for (int k = 0; k < 4; ++k) {
        f32x4 xv = Xn[4 * q + k];
        wrx += (wr[k].x * xv.x + wr[k].y * xv.y) + (wr[k].z * xv.z + wr[k].w * xv.w);
      }
    }

    // ---- per-thread poll of own 4 B-producer flags (one dwordx4) ----
    {
      const unsigned* fp = fBc + c * GR + 4 * rg;
      u32x4 fv;
      for (;;) {
        asm volatile("global_load_dwordx4 %0, %1, off sc0 sc1\n\ts_waitcnt vmcnt(0)"
                     : "=v"(fv) : "v"(fp) : "memory");
        __builtin_amdgcn_sched_barrier(0);
        if (fv.x >= tg && fv.y >= tg && fv.z >= tg && fv.w >= tg) break;
        __builtin_amdgcn_s_sleep(1);
      }
    }
    // ---- read own 4 colsum chunks ----
    {
      float u0, u1, u2, u3;
      const float* baseB = Scol + (size_t)p * GR * N + gcol + c_loc;
      asm volatile("global_load_dword %0, %4, off sc0 sc1\n\t"
                   "global_load_dword %1, %5, off sc0 sc1\n\t"
                   "global_load_dword %2, %6, off sc0 sc1\n\t"
                   "global_load_dword %3, %7, off sc0 sc1\n\t"
                   "s_waitcnt vmcnt(0)"
                   : "=v"(u0), "=v"(u1), "=v"(u2), "=v"(u3)
                   : "v"(baseB + (size_t)(4 * rg + 0) * N),
                     "v"(baseB + (size_t)(4 * rg + 1) * N),
                     "v"(baseB + (size_t)(4 * rg + 2) * N),
                     "v"(baseB + (size_t)(4 * rg + 3) * N)
                   : "memory");
      __builtin_amdgcn_sched_barrier(0);
      SLd[rg][c_loc] = (u0 + u1) + (u2 + u3);
    }
    // safety pollB-row (gates publish A(t+1)): done before sync (e)
    if (tid >= 16 && tid < 32) {
      while (__hip_atomic_load(&fBr[r * GC + (tid - 16)], __ATOMIC_RELAXED,
                               __HIP_MEMORY_SCOPE_AGENT) < tg)
        __builtin_amdgcn_s_sleep(1);
    }
    __syncthreads();  // (d) SLd visible; safety poll done
    if (tid < TB) {
      float s = (SLd[0][tid] + SLd[1][tid]) + (SLd[2][tid] + SLd[3][tid]);
      f_loc[tid] = (s > 1.f) ? 1.f / s : 1.f;  // MAX_PRE = 1
    }
    __syncthreads();  // (e) f_loc visible
  }
}

extern "C" void kernel_launch(void* const* d_in, const int* in_sizes, int n_in,
                              void* d_out, int out_size, void* d_ws, size_t ws_size,
                              hipStream_t stream) {
  const float* X = (const float*)d_in[0];   // inputs [128][1024]
  const float* W = (const float*)d_in[2];   // out_in_fixed [1024][1024]
  float* OUT = (float*)d_out;               // [128][1024] f32

  char* ws = (char*)d_ws;
  // layout: fAr|fAc|fBc|fBr (1KB each, memset) | OutP 256KB | Scol 128KB
  unsigned* fAr = (unsigned*)ws;
  unsigned* fAc = (unsigned*)(ws + 1024);
  unsigned* fBc = (unsigned*)(ws + 2048);
  unsigned* fBr = (unsigned*)(ws + 3072);
  f32x2* OutP = (f32x2*)(ws + 4096);
  float* Scol = (float*)(ws + 4096 + (size_t)2 * GC * N * sizeof(f32x2));

  // flags zero at every (graph-replayed) launch; monotone within a launch.
  // Data buffers need no clear: every read is flag-gated.
  hipMemsetAsync(ws, 0, 4096, stream);

  hipLaunchKernelGGL(rf2d_kernel, dim3(GR * GC), dim3(NT), 0, stream,
                     X, W, OUT, OutP, Scol, fAr, fAc, fBc, fBr);
}